// Round 3
// baseline (527.433 us; speedup 1.0000x reference)
//
#include <hip/hip_runtime.h>

// StyleGAN 3D upsample x2, k=[1,4,6,4,1]/16*2 per axis, fused polyphase:
//   even: o[2i]   = 0.5*(x[i-1]+x[i])
//   odd : o[2i+1] = 0.125*x[i-1] + 0.75*x[i] + 0.125*x[i+1]
// Input fp32 [4,32,48,48,48], output fp32 [4,32,96,96,96].
//
// v4: NO LDS, no barrier. Each thread owns 4 output columns (window
// x[2tx-1..2tx+2] via one dword-aligned float4 load per row), 2 output
// rows, and slides a 3-plane register window along D. Input rows are
// reused across dy out of L1 (3.5 KB/z-step working set); cross-block
// re-reads come from L2/L3 (input is 57 MB, fully L3-resident).
// Removes the stage->barrier->compute serialization that plateaued
// v1/v3 at ~195 us kernel time.

#define IN_D 48
#define IN_H 48
#define IN_W 48
#define NC   128             // N*C = 4*32
#define TD   8               // output D-slab per block (z-layers read: TD+2)
#define TH   16              // H rows per block
#define NTX  24              // threads along W; each -> 4 output floats
#define NTHREADS (NTX * TH)  // 384 = 6 waves

__device__ __forceinline__ float4 f4_even(float4 a, float4 b) {
    return make_float4(0.5f * (a.x + b.x), 0.5f * (a.y + b.y),
                       0.5f * (a.z + b.z), 0.5f * (a.w + b.w));
}
__device__ __forceinline__ float4 f4_odd(float4 a, float4 b, float4 c) {
    return make_float4(0.125f * (a.x + c.x) + 0.75f * b.x,
                       0.125f * (a.y + c.y) + 0.75f * b.y,
                       0.125f * (a.z + c.z) + 0.75f * b.z,
                       0.125f * (a.w + c.w) + 0.75f * b.w);
}

struct Q { float4 E, O; };   // h-even / h-odd row of 4 W-outputs

__global__ __launch_bounds__(NTHREADS, 4)
void upfir3d_kernel(const float* __restrict__ in,
                    float* __restrict__ out) {
    const int tx = threadIdx.x;            // 0..23
    const int ty = threadIdx.y;            // 0..15
    const int bh = blockIdx.x;             // 0..2
    const int dz = blockIdx.y;             // 0..5
    const int nc = blockIdx.z;             // 0..127

    const int ih  = bh * TH + ty;          // center input row, 0..47
    const int id0 = dz * TD;
    const float* base = in + (size_t)nc * (IN_D * IN_H * IN_W);

    // W window: x[2tx-1 .. 2tx+2], one dword-aligned float4 load + edge fixup
    const int off = min(max(2 * tx - 1, 0), IN_W - 4);
    const bool txlo = (tx == 0);
    const bool txhi = (tx == NTX - 1);

    auto loadrow = [&](const float* row) -> float4 {
        float4 v = *reinterpret_cast<const float4*>(row + off);
        if (txlo) v = make_float4(0.0f, v.x, v.y, v.z);   // {0,x0,x1,x2}
        if (txhi) v = make_float4(v.y, v.z, v.w, 0.0f);   // {x45,x46,x47,0}
        return v;
    };

    // WH-combined partials for one input plane gd (zero-plane if OOB):
    //   E = output row 2ih   (h-even): {wE0, wO0, wE1, wO1} at ow=4tx
    //   O = output row 2ih+1 (h-odd)
    auto whpart = [&](int gd) -> Q {
        Q q;
        q.E = make_float4(0.f, 0.f, 0.f, 0.f);
        q.O = q.E;
        if ((unsigned)gd >= (unsigned)IN_D) return q;     // block-uniform
        const float* plane = base + (size_t)gd * (IN_H * IN_W);
        float4 r[3];
#pragma unroll
        for (int dy = 0; dy < 3; ++dy) {
            const int gh = ih - 1 + dy;
            float4 v = make_float4(0.f, 0.f, 0.f, 0.f);
            if ((unsigned)gh < (unsigned)IN_H)
                v = loadrow(plane + gh * IN_W);
            r[dy].x = 0.5f * (v.x + v.y);                  // w even
            r[dy].y = 0.125f * (v.x + v.z) + 0.75f * v.y;  // w odd
            r[dy].z = 0.5f * (v.y + v.z);                  // w even
            r[dy].w = 0.125f * (v.y + v.w) + 0.75f * v.z;  // w odd
        }
        q.E = f4_even(r[0], r[1]);
        q.O = f4_odd(r[0], r[1], r[2]);
        return q;
    };

    Q qm = whpart(id0 - 1);
    Q qc = whpart(id0);

    const int OD = 2 * IN_D, OH = 2 * IN_H, OW = 2 * IN_W;
    const int ow = 4 * tx;                 // 16B-aligned float4 slot
    const int oh = 2 * ih;
    float* ob = out + (size_t)nc * OD * OH * OW;

#pragma unroll
    for (int d = 0; d < TD; ++d) {
        Q qp = whpart(id0 + d + 1);
        const int od = 2 * (id0 + d);

        size_t b0 = ((size_t)od * OH + oh) * OW + ow;          // d-even plane
        *reinterpret_cast<float4*>(ob + b0)      = f4_even(qm.E, qc.E);
        *reinterpret_cast<float4*>(ob + b0 + OW) = f4_even(qm.O, qc.O);

        size_t b1 = b0 + (size_t)OH * OW;                      // d-odd plane
        *reinterpret_cast<float4*>(ob + b1)      = f4_odd(qm.E, qc.E, qp.E);
        *reinterpret_cast<float4*>(ob + b1 + OW) = f4_odd(qm.O, qc.O, qp.O);

        qm = qc;
        qc = qp;
    }
}

extern "C" void kernel_launch(void* const* d_in, const int* in_sizes, int n_in,
                              void* d_out, int out_size, void* d_ws, size_t ws_size,
                              hipStream_t stream) {
    const float* x = (const float*)d_in[0];
    float* out = (float*)d_out;

    dim3 grid(IN_H / TH, IN_D / TD, NC);   // (3, 6, 128) = 2304 blocks
    dim3 block(NTX, TH, 1);                // (24, 16) = 384 threads
    upfir3d_kernel<<<grid, block, 0, stream>>>(x, out);
}

// Round 4
// 509.488 us; speedup vs baseline: 1.0352x; 1.0352x over previous
//
#include <hip/hip_runtime.h>

// StyleGAN 3D upsample x2, k=[1,4,6,4,1]/16*2 per axis, fused polyphase:
//   even: o[2i]   = 0.5*(x[i-1]+x[i])
//   odd : o[2i+1] = 0.125*x[i-1] + 0.75*x[i] + 0.125*x[i+1]
// Input fp32 [4,32,48,48,48], output fp32 [4,32,96,96,96].
//
// v5 = v3 (full-W LDS tile, float4 stores, vectorized staging) with
// register-pressure fixes to reach the 64-VGPR occupancy bucket:
//  - __launch_bounds__(384, 8): allocator targets <=64 VGPR -> with LDS
//    29.4 KB the CU fits 5 blocks (30 waves) instead of a VGPR-capped 2.
//  - 32-bit in-buffer offsets (output < 4 GB) instead of size_t chains.
//  - inner loop stores the d-even plane BEFORE computing qp (d+1 layer),
//    cutting peak liveness by ~8 VGPRs.

#define IN_D 48
#define IN_H 48
#define IN_W 48
#define NC   128             // N*C = 4*32
#define TD   6               // input tile depth per block
#define TH   16              // input tile height per block
#define NTX  24              // threads along W; each covers 2 input cols
#define NTHREADS (NTX * TH)  // 384 = 6 waves
#define LZ (TD + 2)          // 8  (D halo)
#define LY (TH + 2)          // 18 (H halo)
#define LX (IN_W + 2)        // 50 (W halo; halo cols are always zero)
#define LXP (LX + 1)         // 51 padded row stride
#define NROWS (LZ * LY)      // 144 staged rows

__device__ __forceinline__ float4 f4_even(float4 a, float4 b) {
    return make_float4(0.5f * (a.x + b.x), 0.5f * (a.y + b.y),
                       0.5f * (a.z + b.z), 0.5f * (a.w + b.w));
}
__device__ __forceinline__ float4 f4_odd(float4 a, float4 b, float4 c) {
    return make_float4(0.125f * (a.x + c.x) + 0.75f * b.x,
                       0.125f * (a.y + c.y) + 0.75f * b.y,
                       0.125f * (a.z + c.z) + 0.75f * b.z,
                       0.125f * (a.w + c.w) + 0.75f * b.w);
}

struct Q { float4 E, O; };   // h-even / h-odd row of 4 W-outputs

__global__ __launch_bounds__(NTHREADS, 8)
void upfir3d_kernel(const float* __restrict__ in,
                    float* __restrict__ out) {
    __shared__ float lds[NROWS * LXP];     // 144*51*4 = 29376 B

    const int tx = threadIdx.x;            // 0..23
    const int ty = threadIdx.y;            // 0..15
    const int bh = blockIdx.x;             // 0..2
    const int dz = blockIdx.y;             // 0..7
    const int nc = blockIdx.z;             // 0..127

    const int ih0 = bh * TH;
    const int id0 = dz * TD;
    const float* inb = in + (size_t)nc * (IN_D * IN_H * IN_W);

    const int tid = ty * NTX + tx;

    // ---- zero halo columns (col 0 and col 49) ----
    if (tid < 2 * NROWS) {
        int row = tid >> 1;
        int col = (tid & 1) ? (LX - 1) : 0;
        lds[row * LXP + col] = 0.0f;
    }

    // ---- stage interior: 12 float4 per (z,y) row, zero outside D/H bounds ----
    {
        const int q = tid % 12;            // float4 slot within the row
        const int r = tid / 12;            // starting row; stride 32
        for (int row = r; row < NROWS; row += NTHREADS / 12) {
            int z  = row / LY;
            int y  = row - z * LY;
            int gd = id0 - 1 + z;
            int gh = ih0 - 1 + y;
            float4 v = make_float4(0.f, 0.f, 0.f, 0.f);
            if ((unsigned)gd < (unsigned)IN_D && (unsigned)gh < (unsigned)IN_H) {
                unsigned goff = (unsigned)(gd * (IN_H * IN_W) + gh * IN_W + 4 * q);
                v = *reinterpret_cast<const float4*>(inb + goff);
            }
            float* dst = &lds[row * LXP + 1 + 4 * q];
            dst[0] = v.x; dst[1] = v.y; dst[2] = v.z; dst[3] = v.w;
        }
    }
    __syncthreads();

    // ---- per-thread: 2 input columns (2tx, 2tx+1), slide along D ----
    const int ly = ty + 1;
    const int c0 = 2 * tx;                 // LDS col of x[2tx-1]

    // WH-combined partials for one LDS layer z:
    //   E = row oh   (h-even): 4 W-outputs {wE0, wO0, wE1, wO1}
    //   O = row oh+1 (h-odd)
    auto whpart = [&](int z) -> Q {
        const float* p = &lds[(z * LY + (ly - 1)) * LXP + c0];
        float4 r[3];
#pragma unroll
        for (int dy = 0; dy < 3; ++dy) {
            float v0 = p[dy * LXP + 0];
            float v1 = p[dy * LXP + 1];
            float v2 = p[dy * LXP + 2];
            float v3 = p[dy * LXP + 3];
            r[dy].x = 0.5f * (v0 + v1);                    // out 4tx   (w even)
            r[dy].y = 0.125f * (v0 + v2) + 0.75f * v1;     // out 4tx+1 (w odd)
            r[dy].z = 0.5f * (v1 + v2);                    // out 4tx+2 (w even)
            r[dy].w = 0.125f * (v1 + v3) + 0.75f * v2;     // out 4tx+3 (w odd)
        }
        Q q;
        q.E = f4_even(r[0], r[1]);
        q.O = f4_odd(r[0], r[1], r[2]);
        return q;
    };

    Q qm = whpart(0);        // layer id0-1
    Q qc = whpart(1);        // layer id0

    const int OD = 2 * IN_D, OH = 2 * IN_H, OW = 2 * IN_W;
    float* ob = out + (size_t)nc * (OD * OH * OW);
    // 32-bit in-buffer offsets (per-nc slab is 3.4 MB)
    unsigned b0 = (unsigned)((2 * id0 * OH + 2 * (ih0 + ty)) * OW + 4 * tx);
    const unsigned dstep = (unsigned)(2 * OH * OW);    // advance 2 planes
    const unsigned pstep = (unsigned)(OH * OW);        // even->odd plane

#pragma unroll
    for (int d = 0; d < TD; ++d) {
        // d-even plane depends only on qm,qc -> store before loading qp
        *reinterpret_cast<float4*>(ob + b0)      = f4_even(qm.E, qc.E);
        *reinterpret_cast<float4*>(ob + b0 + OW) = f4_even(qm.O, qc.O);

        Q qp = whpart(d + 2);              // layer id0+d+1

        *reinterpret_cast<float4*>(ob + b0 + pstep)      = f4_odd(qm.E, qc.E, qp.E);
        *reinterpret_cast<float4*>(ob + b0 + pstep + OW) = f4_odd(qm.O, qc.O, qp.O);

        qm = qc;
        qc = qp;
        b0 += dstep;
    }
}

extern "C" void kernel_launch(void* const* d_in, const int* in_sizes, int n_in,
                              void* d_out, int out_size, void* d_ws, size_t ws_size,
                              hipStream_t stream) {
    const float* x = (const float*)d_in[0];
    float* out = (float*)d_out;

    dim3 grid(IN_H / TH, IN_D / TD, NC);   // (3, 8, 128) = 3072 blocks
    dim3 block(NTX, TH, 1);                // (24, 16) = 384 threads
    upfir3d_kernel<<<grid, block, 0, stream>>>(x, out);
}

// Round 5
// 480.491 us; speedup vs baseline: 1.0977x; 1.0603x over previous
//
#include <hip/hip_runtime.h>

// StyleGAN 3D upsample x2, k=[1,4,6,4,1]/16*2 per axis, fused polyphase:
//   even: o[2i]   = 0.5*(x[i-1]+x[i])
//   odd : o[2i+1] = 0.125*x[i-1] + 0.75*x[i] + 0.125*x[i+1]
// Input fp32 [4,32,48,48,48], output fp32 [4,32,96,96,96].
//
// v6: one OUTPUT row per thread (ty = output row; parity selects H-weights),
// halving live filter state (3x float4 vs 3x {E,O} pairs) to land naturally
// in the <=64-VGPR bucket -> 8 waves/SIMD -> 5 blocks/CU (30 waves), vs
// v3's VGPR-capped 2 blocks (12 waves). Also: every wave store is ONE
// contiguous 1024B segment (ty-major = consecutive output rows, 24 tx
// cover the full 96-float row), and LDS stride is even (52) so each
// 4-float window is 2x ds_read_b64 (same-row lanes broadcast).

#define IN_D 48
#define IN_H 48
#define IN_W 48
#define NC   128              // N*C = 4*32
#define TD   8                // input D-slab per block
#define THI  8                // input H rows per block (16 output rows)
#define NTX  24               // threads along W: 4 output floats each
#define NTY  16               // threads = output rows per block
#define NTHREADS (NTX * NTY)  // 384 = 6 waves
#define LZ (TD + 2)           // 10 (D halo)
#define LY (THI + 2)          // 10 (H halo)
#define LXP 52                // even padded row stride (cols 0..49 used)
#define NROWS (LZ * LY)       // 100 staged rows; LDS = 100*52*4 = 20.8 KB

__device__ __forceinline__ float4 f4_even(float4 a, float4 b) {
    return make_float4(0.5f * (a.x + b.x), 0.5f * (a.y + b.y),
                       0.5f * (a.z + b.z), 0.5f * (a.w + b.w));
}
__device__ __forceinline__ float4 f4_odd(float4 a, float4 b, float4 c) {
    return make_float4(0.125f * (a.x + c.x) + 0.75f * b.x,
                       0.125f * (a.y + c.y) + 0.75f * b.y,
                       0.125f * (a.z + c.z) + 0.75f * b.z,
                       0.125f * (a.w + c.w) + 0.75f * b.w);
}

__global__ __launch_bounds__(NTHREADS)
void upfir3d_kernel(const float* __restrict__ in,
                    float* __restrict__ out) {
    __shared__ float lds[NROWS * LXP];

    const int tx = threadIdx.x;            // 0..23
    const int ty = threadIdx.y;            // 0..15 -> output row 2*ih0+ty
    const int bh = blockIdx.x;             // 0..5
    const int dz = blockIdx.y;             // 0..5
    const int nc = blockIdx.z;             // 0..127

    const int ih0 = bh * THI;
    const int id0 = dz * TD;
    const float* inb = in + (size_t)nc * (IN_D * IN_H * IN_W);

    const int tid = ty * NTX + tx;

    // ---- zero halo columns (col 0 and col 49) ----
    if (tid < 2 * NROWS) {
        int row = tid >> 1;
        int col = (tid & 1) ? 49 : 0;
        lds[row * LXP + col] = 0.0f;
    }

    // ---- stage interior: 12 float4 per (z,y) row, zero outside D/H ----
    {
        const int q = tid % 12;            // float4 slot within the row
        for (int row = tid / 12; row < NROWS; row += NTHREADS / 12) {
            int z  = row / LY;
            int y  = row - z * LY;
            int gd = id0 - 1 + z;
            int gh = ih0 - 1 + y;
            float4 v = make_float4(0.f, 0.f, 0.f, 0.f);
            if ((unsigned)gd < (unsigned)IN_D && (unsigned)gh < (unsigned)IN_H) {
                v = *reinterpret_cast<const float4*>(
                        inb + ((size_t)gd * IN_H + gh) * IN_W + 4 * q);
            }
            float* dst = &lds[row * LXP + 1 + 4 * q];
            dst[0] = v.x; dst[1] = v.y; dst[2] = v.z; dst[3] = v.w;
        }
    }
    __syncthreads();

    // ---- per-thread: one output row, 4 W-outputs, slide along D ----
    const int p   = ty & 1;                // 0: h-even row, 1: h-odd row
    const float wga = p ? 0.125f : 0.5f;   // weight of r[ih-1]
    const float wgb = p ? 0.75f  : 0.5f;   // weight of r[ih]
    const float wgc = p ? 0.125f : 0.0f;   // weight of r[ih+1]
    const int yy0 = ty >> 1;               // LDS y-row holding input row ih-1
    const int cx  = 2 * tx;                // even -> 8B-aligned float2 reads

    // W-filter 3 input rows of one z-layer, H-combine with (wga,wgb,wgc):
    // returns 4 consecutive W-outputs for this thread's output row.
    auto whpart = [&](int z) -> float4 {
        const float* pp = &lds[(z * LY + yy0) * LXP + cx];
        float4 q4 = make_float4(0.f, 0.f, 0.f, 0.f);
#pragma unroll
        for (int dy = 0; dy < 3; ++dy) {
            const float wt = (dy == 0) ? wga : (dy == 1) ? wgb : wgc;
            float2 a = *reinterpret_cast<const float2*>(pp + dy * LXP);
            float2 b = *reinterpret_cast<const float2*>(pp + dy * LXP + 2);
            float w0 = 0.5f   * (a.x + a.y);                 // ow 4tx
            float w1 = 0.125f * (a.x + b.x) + 0.75f * a.y;   // ow 4tx+1
            float w2 = 0.5f   * (a.y + b.x);                 // ow 4tx+2
            float w3 = 0.125f * (a.y + b.y) + 0.75f * b.x;   // ow 4tx+3
            q4.x += wt * w0; q4.y += wt * w1;
            q4.z += wt * w2; q4.w += wt * w3;
        }
        return q4;
    };

    float4 qm = whpart(0);   // layer id0-1
    float4 qc = whpart(1);   // layer id0

    const int OH = 2 * IN_H, OW = 2 * IN_W;
    const int orow = 2 * ih0 + ty;
    float* ob = out + (size_t)nc * (2 * IN_D * OH * OW)
                    + (size_t)orow * OW + 4 * tx;
    const size_t plane = (size_t)OH * OW;

#pragma unroll
    for (int d = 0; d < TD; ++d) {
        float4 qp = whpart(d + 2);         // layer id0+d+1
        const int od = 2 * (id0 + d);

        *reinterpret_cast<float4*>(ob + (size_t)od * plane)       = f4_even(qm, qc);
        *reinterpret_cast<float4*>(ob + (size_t)(od + 1) * plane) = f4_odd(qm, qc, qp);

        qm = qc;
        qc = qp;
    }
}

extern "C" void kernel_launch(void* const* d_in, const int* in_sizes, int n_in,
                              void* d_out, int out_size, void* d_ws, size_t ws_size,
                              hipStream_t stream) {
    const float* x = (const float*)d_in[0];
    float* out = (float*)d_out;

    dim3 grid(IN_H / THI, IN_D / TD, NC);  // (6, 6, 128) = 4608 blocks
    dim3 block(NTX, NTY, 1);               // (24, 16) = 384 threads
    upfir3d_kernel<<<grid, block, 0, stream>>>(x, out);
}